// Round 6
// baseline (153.876 us; speedup 1.0000x reference)
//
#include <hip/hip_runtime.h>
#include <math.h>

static constexpr int kN = 8192;
static constexpr int kC = 128;
static constexpr int kB = 16;
static constexpr float kScale = 0.5f / 1048576.0f; // 1/(C*N) * 0.5 (combine fold)
static constexpr double kTwoPi = 6.28318530717958647692;

#define C8 0.70710678118654752f

__device__ __forceinline__ float2 cadd(float2 a, float2 b){ return make_float2(a.x+b.x, a.y+b.y); }
__device__ __forceinline__ float2 csub(float2 a, float2 b){ return make_float2(a.x-b.x, a.y-b.y); }
__device__ __forceinline__ float2 cmul(float2 a, float2 b){ return make_float2(a.x*b.x-a.y*b.y, a.x*b.y+a.y*b.x); }
__device__ __forceinline__ float2 cconj(float2 a){ return make_float2(a.x, -a.y); }

// conflict-floor swizzle (validated r3-r5)
__device__ __forceinline__ int swz(int n){ return n ^ ((n>>4)&7) ^ (((n>>6)&7)<<3); }

// e^{+2pi i m/4096}, m in [0,2048)
__device__ __forceinline__ float2 W2048(const float2* T, int m){
    float2 tt = T[m & 1023];
    return (m & 1024) ? make_float2(-tt.y, tt.x) : tt;
}

// 8-point DFT, A_k = sum_j a_j e^{SGN*2pi i jk/8}, in place
template<int SGN>
__device__ __forceinline__ void dft8(float2* a){
    float2 s0=cadd(a[0],a[4]), s1=csub(a[0],a[4]);
    float2 s2=cadd(a[2],a[6]), s3=csub(a[2],a[6]);
    float2 E0=cadd(s0,s2), E2=csub(s0,s2);
    float2 j3 = (SGN>0)? make_float2(-s3.y, s3.x) : make_float2(s3.y, -s3.x);
    float2 E1=cadd(s1,j3), E3=csub(s1,j3);
    float2 t0=cadd(a[1],a[5]), t1=csub(a[1],a[5]);
    float2 t2=cadd(a[3],a[7]), t3=csub(a[3],a[7]);
    float2 O0=cadd(t0,t2), O2=csub(t0,t2);
    float2 k3 = (SGN>0)? make_float2(-t3.y, t3.x) : make_float2(t3.y, -t3.x);
    float2 O1=cadd(t1,k3), O3=csub(t1,k3);
    float2 W1 = (SGN>0)? make_float2(C8*(O1.x-O1.y), C8*(O1.x+O1.y))
                       : make_float2(C8*(O1.x+O1.y), C8*(O1.y-O1.x));
    float2 W2 = (SGN>0)? make_float2(-O2.y, O2.x) : make_float2(O2.y, -O2.x);
    float2 W3 = (SGN>0)? make_float2(C8*(-O3.x-O3.y), C8*(O3.x-O3.y))
                       : make_float2(C8*(O3.y-O3.x), C8*(-O3.x-O3.y));
    a[0]=cadd(E0,O0); a[4]=csub(E0,O0);
    a[1]=cadd(E1,W1); a[5]=csub(E1,W1);
    a[2]=cadd(E2,W2); a[6]=csub(E2,W2);
    a[3]=cadd(E3,W3); a[7]=csub(E3,W3);
}

// apply w^k, k=1..7, to BOTH rows; tree built once
__device__ __forceinline__ void twid_apply2(float2* a, float2* b, float2 w1){
    float2 w2=cmul(w1,w1);
    float2 w3=cmul(w2,w1), w4=cmul(w2,w2);
    float2 w5=cmul(w2,w3), w6=cmul(w3,w3), w7=cmul(w3,w4);
    a[1]=cmul(a[1],w1); a[2]=cmul(a[2],w2); a[3]=cmul(a[3],w3);
    a[4]=cmul(a[4],w4); a[5]=cmul(a[5],w5); a[6]=cmul(a[6],w6); a[7]=cmul(a[7],w7);
    b[1]=cmul(b[1],w1); b[2]=cmul(b[2],w2); b[3]=cmul(b[3],w3);
    b[4]=cmul(b[4],w4); b[5]=cmul(b[5],w5); b[6]=cmul(b[6],w6); b[7]=cmul(b[7],w7);
}

// tanh-form GELU
__device__ __forceinline__ float gelu_fast(float v){
    float z = v*(0.7978845608028654f + 0.0356774081363001f*v*v);
    float e = __builtin_amdgcn_exp2f(-2.8853900817779268f * z);
    return v / (1.0f + e);
}

// Kernel 1: two rows/WG packed float4. Barriers minimized: h64/h8/h1 stage
// boundaries are WAVE-LOCAL (wave w only touches its own 512-block there),
// so only the h512<->h64 crossings + stats need __syncthreads (4 total).
// Output: Z' (4096-pt forward FFT of GELU'd signal), natural order, cols 0..4095.
__global__ __launch_bounds__(512, 4) void k1_row(
    const float* __restrict__ xr, const float* __restrict__ xi,
    const float* __restrict__ gamma, const float* __restrict__ beta,
    float* __restrict__ outR, float* __restrict__ outI)
{
    __shared__ float4 buf[4096];  // 64 KiB packed row-pair
    __shared__ float2 T[1024];    // 8 KiB: e^{+2pi i m/4096}
    __shared__ float4 sred[8];    // stats partials

    const int t    = threadIdx.x;
    const int row0 = blockIdx.x * 2;

    for (int i = t; i < 1024; i += 512) {
        float s, c;
        sincosf((float)(kTwoPi/4096.0 * (double)i), &s, &c);
        T[i] = make_float2(c, s);
    }
    __syncthreads();                                  // (1) T ready

    const float2 E = make_float2(0.9999997058628822f, 7.669903187427045e-4f); // e^{+i pi/4096}
    const int l   = t & 63;
    const int s64 = ((t>>6)*512 + l) ^ (l>>4);
    const int u = t & 7, G = t >> 3, g = G & 7;
    const int s8 = (G<<6) + (g<<3) + (u ^ ((G&1)<<2));
    const int s1 = (t<<3) ^ ((t>>1)&7) ^ (((t>>3)&7)<<3);
    const int s0 = swz(t);

    float2 v0[8], v1[8];

    const float* r0R = xr + (size_t)row0 * kN;
    const float* r0I = xi + (size_t)row0 * kN;
    const float* r1R = r0R + kN;
    const float* r1I = r0I + kN;

    // ---- pre-combine (scale-free; instnorm absorbs) + DIF h=512 ----
    #pragma unroll
    for (int j = 0; j < 8; ++j) {
        int k   = t + (j<<9);
        int km  = (kN - k) & (kN-1);
        int km2 = 4096 - k;
        float2 w = W2048(T, k>>1);
        if (t & 1) w = cmul(w, E);
        {
            float2 Hk  = make_float2(r0R[k]+r0R[km],       r0I[k]-r0I[km]);
            float2 Hk2 = make_float2(r0R[k+4096]+r0R[km2], r0I[k+4096]-r0I[km2]);
            float2 S = cadd(Hk,Hk2), D = csub(Hk,Hk2);
            float2 P = cmul(D, w);
            v0[j] = make_float2(S.x - P.y, S.y + P.x);
        }
        {
            float2 Hk  = make_float2(r1R[k]+r1R[km],       r1I[k]-r1I[km]);
            float2 Hk2 = make_float2(r1R[k+4096]+r1R[km2], r1I[k+4096]-r1I[km2]);
            float2 S = cadd(Hk,Hk2), D = csub(Hk,Hk2);
            float2 P = cmul(D, w);
            v1[j] = make_float2(S.x - P.y, S.y + P.x);
        }
    }
    dft8<1>(v0); dft8<1>(v1);
    twid_apply2(v0, v1, T[t]);
    #pragma unroll
    for (int j = 0; j < 8; ++j)
        buf[s0 + (j<<9)] = make_float4(v0[j].x, v0[j].y, v1[j].x, v1[j].y);
    __syncthreads();                                  // (2) h512 -> h64 crossing

    // ---- DIF h=64 (wave-local from here) ----
    #pragma unroll
    for (int j = 0; j < 8; ++j) {
        float4 p = buf[s64 ^ ((j<<6)|(j<<3)|((j&1)<<2))];
        v0[j] = make_float2(p.x, p.y); v1[j] = make_float2(p.z, p.w);
    }
    dft8<1>(v0); dft8<1>(v1);
    twid_apply2(v0, v1, T[l<<3]);
    #pragma unroll
    for (int j = 0; j < 8; ++j)
        buf[s64 ^ ((j<<6)|(j<<3)|((j&1)<<2))] = make_float4(v0[j].x, v0[j].y, v1[j].x, v1[j].y);
    __builtin_amdgcn_wave_barrier();

    // ---- DIF h=8 ----
    #pragma unroll
    for (int j = 0; j < 8; ++j) {
        float4 p = buf[s8 ^ ((j<<3)|(j>>1))];
        v0[j] = make_float2(p.x, p.y); v1[j] = make_float2(p.z, p.w);
    }
    dft8<1>(v0); dft8<1>(v1);
    twid_apply2(v0, v1, T[u<<6]);
    #pragma unroll
    for (int j = 0; j < 8; ++j)
        buf[s8 ^ ((j<<3)|(j>>1))] = make_float4(v0[j].x, v0[j].y, v1[j].x, v1[j].y);
    __builtin_amdgcn_wave_barrier();

    // ---- DIF h=1 (stays in regs) ----
    #pragma unroll
    for (int j = 0; j < 8; ++j) {
        float4 p = buf[s1 ^ j];
        v0[j] = make_float2(p.x, p.y); v1[j] = make_float2(p.z, p.w);
    }
    dft8<1>(v0); dft8<1>(v1);

    // ---- instance norm stats (order-agnostic) ----
    float ps0 = 0.f, pq0 = 0.f, ps1 = 0.f, pq1 = 0.f;
    #pragma unroll
    for (int j = 0; j < 8; ++j) {
        ps0 += v0[j].x + v0[j].y;  pq0 += v0[j].x*v0[j].x + v0[j].y*v0[j].y;
        ps1 += v1[j].x + v1[j].y;  pq1 += v1[j].x*v1[j].x + v1[j].y*v1[j].y;
    }
    #pragma unroll
    for (int off = 32; off >= 1; off >>= 1) {
        ps0 += __shfl_down(ps0, off);  pq0 += __shfl_down(pq0, off);
        ps1 += __shfl_down(ps1, off);  pq1 += __shfl_down(pq1, off);
    }
    if ((t & 63) == 0) sred[t>>6] = make_float4(ps0, pq0, ps1, pq1);
    __syncthreads();                                  // (3) stats ready
    float sum0=0.f, sq0=0.f, sum1=0.f, sq1=0.f;
    #pragma unroll
    for (int w = 0; w < 8; ++w) {
        float4 p = sred[w];
        sum0 += p.x; sq0 += p.y; sum1 += p.z; sq1 += p.w;
    }
    {
        float mean = sum0 * (1.0f/8192.0f);
        float var  = sq0  * (1.0f/8192.0f) - mean*mean;
        float gg = gamma[row0 & (kC-1)] * rsqrtf(var + 1e-5f);
        float bb = beta[row0 & (kC-1)] - mean * gg;
        #pragma unroll
        for (int j = 0; j < 8; ++j) {
            v0[j].x = gelu_fast(v0[j].x * gg + bb);
            v0[j].y = gelu_fast(v0[j].y * gg + bb);
        }
    }
    {
        float mean = sum1 * (1.0f/8192.0f);
        float var  = sq1  * (1.0f/8192.0f) - mean*mean;
        float gg = gamma[(row0+1) & (kC-1)] * rsqrtf(var + 1e-5f);
        float bb = beta[(row0+1) & (kC-1)] - mean * gg;
        #pragma unroll
        for (int j = 0; j < 8; ++j) {
            v1[j].x = gelu_fast(v1[j].x * gg + bb);
            v1[j].y = gelu_fast(v1[j].y * gg + bb);
        }
    }

    // ---- forward: DIT h=1 ----
    dft8<-1>(v0); dft8<-1>(v1);
    #pragma unroll
    for (int j = 0; j < 8; ++j)
        buf[s1 ^ j] = make_float4(v0[j].x, v0[j].y, v1[j].x, v1[j].y);
    __builtin_amdgcn_wave_barrier();

    // ---- DIT h=8 ----
    #pragma unroll
    for (int j = 0; j < 8; ++j) {
        float4 p = buf[s8 ^ ((j<<3)|(j>>1))];
        v0[j] = make_float2(p.x, p.y); v1[j] = make_float2(p.z, p.w);
    }
    twid_apply2(v0, v1, cconj(T[u<<6]));
    dft8<-1>(v0); dft8<-1>(v1);
    #pragma unroll
    for (int j = 0; j < 8; ++j)
        buf[s8 ^ ((j<<3)|(j>>1))] = make_float4(v0[j].x, v0[j].y, v1[j].x, v1[j].y);
    __builtin_amdgcn_wave_barrier();

    // ---- DIT h=64 ----
    #pragma unroll
    for (int j = 0; j < 8; ++j) {
        float4 p = buf[s64 ^ ((j<<6)|(j<<3)|((j&1)<<2))];
        v0[j] = make_float2(p.x, p.y); v1[j] = make_float2(p.z, p.w);
    }
    twid_apply2(v0, v1, cconj(T[l<<3]));
    dft8<-1>(v0); dft8<-1>(v1);
    #pragma unroll
    for (int j = 0; j < 8; ++j)
        buf[s64 ^ ((j<<6)|(j<<3)|((j&1)<<2))] = make_float4(v0[j].x, v0[j].y, v1[j].x, v1[j].y);
    __syncthreads();                                  // (4) h64 -> h512 crossing

    // ---- DIT h=512: Z' natural order, straight from regs to global ----
    #pragma unroll
    for (int j = 0; j < 8; ++j) {
        float4 p = buf[s0 + (j<<9)];
        v0[j] = make_float2(p.x, p.y); v1[j] = make_float2(p.z, p.w);
    }
    twid_apply2(v0, v1, cconj(T[t]));
    dft8<-1>(v0); dft8<-1>(v1);

    float* o0R = outR + (size_t)row0 * kN;
    float* o0I = outI + (size_t)row0 * kN;
    float* o1R = o0R + kN;
    float* o1I = o0I + kN;
    #pragma unroll
    for (int j = 0; j < 8; ++j) {
        int k = t + (j<<9);
        o0R[k] = v0[j].x;  o0I[k] = v0[j].y;
        o1R[k] = v1[j].x;  o1I[k] = v1[j].y;
    }
}

// Kernel 2: per (b, 32-wide colA tile): read Z' column-pairs (colA, 4096-colA),
// build Y[colA], Y[4096-colA] via rfft post-combine (S,P shared per pair),
// 128-pt FFT along c on all 64 columns, scale + bit-rev + Hermitian-mirror writes.
__global__ __launch_bounds__(256, 2) void k2_col(float* __restrict__ outR,
                                                 float* __restrict__ outI)
{
    __shared__ float2 tile[kC][64];  // 64 KiB
    __shared__ float2 tw[64];

    const int tid  = threadIdx.x;
    const int b    = blockIdx.y;
    const int k0   = blockIdx.x << 5;       // 0..2048 step 32 (65 blocks)
    const int j    = tid & 31;
    const int g    = tid >> 5;              // 0..7
    const int colA = k0 + j;
    const bool valid = (colA <= 2048);      // only block 64 has invalid lanes
    const int colB = (4096 - colA) & 4095;

    if (tid < 64) {
        float s, c;
        sincosf((float)(kTwoPi/128.0 * (double)tid), &s, &c);
        tw[tid] = make_float2(c, -s);
    }

    // w = e^{-i pi colA/4096}
    float ws, wc;
    sincosf((float)(-kTwoPi/8192.0 * (double)colA), &ws, &wc);

    float* baseR = outR + (size_t)b * kC * kN;
    float* baseI = outI + (size_t)b * kC * kN;

    for (int c = g; c < kC; c += 8) {
        float2 YA = make_float2(0.f, 0.f), YB = make_float2(0.f, 0.f);
        if (valid) {
            size_t offA = (size_t)c * kN + colA;
            size_t offB = (size_t)c * kN + colB;
            float Zx  = baseR[offA], Zy  = baseI[offA];
            float Zmx = baseR[offB], Zmy = baseI[offB];
            float Sx = Zx + Zmx, Sy = Zy - Zmy;
            float Dx = Zx - Zmx, Dy = Zy + Zmy;
            float Px = Dx*wc - Dy*ws, Py = Dx*ws + Dy*wc;
            YA = make_float2(Sx + Py,  Sy - Px);     // 2*Y[colA]
            YB = make_float2(Sx - Py, -Sy - Px);     // 2*Y[4096-colA]
        }
        tile[c][j]      = YA;
        tile[c][j + 32] = YB;
    }
    __syncthreads();

    // 128-pt forward DIF FFT along c, all 64 columns
    const int kc = tid & 63;
    const int gg = tid >> 6;                // 0..3
    for (int st = 7; st >= 1; --st) {
        const int h = 1 << (st-1);
        #pragma unroll
        for (int s = 0; s < 16; ++s) {
            int q   = gg + (s<<2);
            int pos = q & (h-1);
            int i0  = ((q >> (st-1)) << st) + pos;
            int i1  = i0 + h;
            float2 a = tile[i0][kc], bb = tile[i1][kc];
            float2 w = tw[pos << (7-st)];
            tile[i0][kc] = cadd(a, bb);
            tile[i1][kc] = cmul(csub(a, bb), w);
        }
        __syncthreads();
    }

    // write out: column kc maps to kk (A half: k0+kc; B half: 4096-(k0+kc-32))
    const int cA = (kc < 32) ? (k0 + kc) : (k0 + kc - 32);
    const int kk = (kc < 32) ? cA : (4096 - cA);
    if (cA <= 2048) {
        for (int p = gg; p < kC; p += 4) {
            int f = (int)(__brev((unsigned)p) >> 25);
            float2 v = tile[p][kc];
            v.x *= kScale; v.y *= kScale;
            size_t off = (size_t)f * kN + kk;
            if (kk == 0 || kk == 4096) {
                baseR[off] = v.x; baseI[off] = 0.f;
            } else {
                baseR[off] = v.x; baseI[off] = v.y;
                size_t offm = (size_t)f * kN + (kN - kk);
                baseR[offm] = v.x; baseI[offm] = -v.y;
            }
        }
    }
}

extern "C" void kernel_launch(void* const* d_in, const int* in_sizes, int n_in,
                              void* d_out, int out_size, void* d_ws, size_t ws_size,
                              hipStream_t stream)
{
    const float* xr    = (const float*)d_in[0];
    const float* xi    = (const float*)d_in[1];
    const float* gamma = (const float*)d_in[2];
    const float* beta  = (const float*)d_in[3];

    float* outR = (float*)d_out;
    float* outI = outR + (size_t)kB * kC * kN;

    k1_row<<<kB * kC / 2, 512, 0, stream>>>(xr, xi, gamma, beta, outR, outI);
    k2_col<<<dim3(65, kB), 256, 0, stream>>>(outR, outI);
}

// Round 7
// 117.612 us; speedup vs baseline: 1.3083x; 1.3083x over previous
//
#include <hip/hip_runtime.h>
#include <math.h>

static constexpr int kN = 8192;
static constexpr int kC = 128;
static constexpr int kB = 16;
static constexpr float kScale = 0.5f / 1048576.0f; // 1/(C*N) * 0.5 (post-combine fold)
static constexpr double kTwoPi = 6.28318530717958647692;

#define C8 0.70710678118654752f

typedef float v2f __attribute__((ext_vector_type(2)));

__device__ __forceinline__ v2f mk2(float x, float y){ v2f r; r.x = x; r.y = y; return r; }
// i*a and -i*a
__device__ __forceinline__ v2f imul(v2f a){ return mk2(-a.y, a.x); }
__device__ __forceinline__ v2f mimul(v2f a){ return mk2(a.y, -a.x); }
__device__ __forceinline__ v2f cconj(v2f a){ return mk2(a.x, -a.y); }
// complex multiply via packed ops: re=a.x*b, im=a.y*b.yx, r = re + (-im.x, im.y)
__device__ __forceinline__ v2f cmul(v2f a, v2f b){
    v2f re = a.x * b;
    v2f im = a.y * b.yx;
    return re + mk2(-im.x, im.y);
}

// conflict-floor swizzle (validated r3-r5)
__device__ __forceinline__ int swz(int n){ return n ^ ((n>>4)&7) ^ (((n>>6)&7)<<3); }

// e^{+2pi i m/4096}, m in [0,2048)
__device__ __forceinline__ v2f W2048(const v2f* T, int m){
    v2f tt = T[m & 1023];
    return (m & 1024) ? imul(tt) : tt;
}

// 8-point DFT, A_k = sum_j a_j e^{SGN*2pi i jk/8}, in place
template<int SGN>
__device__ __forceinline__ void dft8(v2f* a){
    v2f s0=a[0]+a[4], s1=a[0]-a[4];
    v2f s2=a[2]+a[6], s3=a[2]-a[6];
    v2f E0=s0+s2, E2=s0-s2;
    v2f j3 = (SGN>0)? imul(s3) : mimul(s3);
    v2f E1=s1+j3, E3=s1-j3;
    v2f t0=a[1]+a[5], t1=a[1]-a[5];
    v2f t2=a[3]+a[7], t3=a[3]-a[7];
    v2f O0=t0+t2, O2=t0-t2;
    v2f k3 = (SGN>0)? imul(t3) : mimul(t3);
    v2f O1=t1+k3, O3=t1-k3;
    v2f W1, W2, W3;
    if (SGN>0){
        W1 = C8 * (O1.xx + mk2(-O1.y, O1.y));        // C8*(x-y, x+y)
        W2 = imul(O2);
        W3 = C8 * (mk2(-O3.x, O3.x) - O3.yy);        // C8*(-x-y, x-y)
    } else {
        W1 = C8 * (O1.yy + mk2(O1.x, -O1.x));        // C8*(x+y, y-x)
        W2 = mimul(O2);
        W3 = C8 * (mk2(O3.y, -O3.y) - O3.xx);        // C8*(y-x, -x-y)
    }
    a[0]=E0+O0; a[4]=E0-O0;
    a[1]=E1+W1; a[5]=E1-W1;
    a[2]=E2+W2; a[6]=E2-W2;
    a[3]=E3+W3; a[7]=E3-W3;
}

// apply w^k, k=1..7, to BOTH rows; tree built once
__device__ __forceinline__ void twid_apply2(v2f* a, v2f* b, v2f w1){
    v2f w2=cmul(w1,w1);
    v2f w3=cmul(w2,w1), w4=cmul(w2,w2);
    v2f w5=cmul(w2,w3), w6=cmul(w3,w3), w7=cmul(w3,w4);
    a[1]=cmul(a[1],w1); a[2]=cmul(a[2],w2); a[3]=cmul(a[3],w3);
    a[4]=cmul(a[4],w4); a[5]=cmul(a[5],w5); a[6]=cmul(a[6],w6); a[7]=cmul(a[7],w7);
    b[1]=cmul(b[1],w1); b[2]=cmul(b[2],w2); b[3]=cmul(b[3],w3);
    b[4]=cmul(b[4],w4); b[5]=cmul(b[5],w5); b[6]=cmul(b[6],w6); b[7]=cmul(b[7],w7);
}

// tanh-form GELU on both components
__device__ __forceinline__ v2f gelu2(v2f v){
    v2f z = v * (0.7978845608028654f + 0.0356774081363001f * v * v);
    float e0 = __builtin_amdgcn_exp2f(-2.8853900817779268f * z.x);
    float e1 = __builtin_amdgcn_exp2f(-2.8853900817779268f * z.y);
    return mk2(v.x / (1.0f + e0), v.y / (1.0f + e1));
}

// Kernel 1: TWO rows per workgroup, PACKED as float4 in LDS (r5 structure);
// all complex arithmetic in v2f for packed-f32 codegen.
__global__ __launch_bounds__(512, 4) void k1_row(
    const float* __restrict__ xr, const float* __restrict__ xi,
    const float* __restrict__ gamma, const float* __restrict__ beta,
    float* __restrict__ outR, float* __restrict__ outI)
{
    __shared__ float4 buf[4096];  // 64 KiB packed row-pair
    __shared__ v2f T[1024];       // 8 KiB: e^{+2pi i m/4096}

    const int t    = threadIdx.x;
    const int row0 = blockIdx.x * 2;

    for (int i = t; i < 1024; i += 512) {
        float s, c;
        sincosf((float)(kTwoPi/4096.0 * (double)i), &s, &c);
        T[i] = mk2(c, s);
    }
    __syncthreads();

    const v2f E = mk2(0.9999997058628822f, 7.669903187427045e-4f); // e^{+i pi/4096}
    const int l   = t & 63;
    const int s64 = ((t>>6)*512 + l) ^ (l>>4);
    const int u = t & 7, G = t >> 3, g = G & 7;
    const int s8 = (G<<6) + (g<<3) + (u ^ ((G&1)<<2));
    const int s1 = (t<<3) ^ ((t>>1)&7) ^ (((t>>3)&7)<<3);
    const int s0 = swz(t);

    v2f v0[8], v1[8];

    const float* r0R = xr + (size_t)row0 * kN;
    const float* r0I = xi + (size_t)row0 * kN;
    const float* r1R = r0R + kN;
    const float* r1I = r0I + kN;

    // ---- pre-combine (scale-free; instnorm absorbs) + DIF h=512 ----
    #pragma unroll
    for (int j = 0; j < 8; ++j) {
        int k   = t + (j<<9);
        int km  = (kN - k) & (kN-1);
        int km2 = 4096 - k;
        v2f w = W2048(T, k>>1);
        if (t & 1) w = cmul(w, E);
        {
            v2f Hk  = mk2(r0R[k]+r0R[km],       r0I[k]-r0I[km]);
            v2f Hk2 = mk2(r0R[k+4096]+r0R[km2], r0I[k+4096]-r0I[km2]);
            v2f S = Hk + Hk2, D = Hk - Hk2;
            v2f P = cmul(D, w);
            v0[j] = S + imul(P);
        }
        {
            v2f Hk  = mk2(r1R[k]+r1R[km],       r1I[k]-r1I[km]);
            v2f Hk2 = mk2(r1R[k+4096]+r1R[km2], r1I[k+4096]-r1I[km2]);
            v2f S = Hk + Hk2, D = Hk - Hk2;
            v2f P = cmul(D, w);
            v1[j] = S + imul(P);
        }
    }
    dft8<1>(v0); dft8<1>(v1);
    twid_apply2(v0, v1, T[t]);
    #pragma unroll
    for (int j = 0; j < 8; ++j)
        buf[s0 + (j<<9)] = make_float4(v0[j].x, v0[j].y, v1[j].x, v1[j].y);
    __syncthreads();

    // ---- DIF h=64 ----
    #pragma unroll
    for (int j = 0; j < 8; ++j) {
        float4 p = buf[s64 ^ ((j<<6)|(j<<3)|((j&1)<<2))];
        v0[j] = mk2(p.x, p.y); v1[j] = mk2(p.z, p.w);
    }
    dft8<1>(v0); dft8<1>(v1);
    twid_apply2(v0, v1, T[l<<3]);
    #pragma unroll
    for (int j = 0; j < 8; ++j)
        buf[s64 ^ ((j<<6)|(j<<3)|((j&1)<<2))] = make_float4(v0[j].x, v0[j].y, v1[j].x, v1[j].y);
    __syncthreads();

    // ---- DIF h=8 ----
    #pragma unroll
    for (int j = 0; j < 8; ++j) {
        float4 p = buf[s8 ^ ((j<<3)|(j>>1))];
        v0[j] = mk2(p.x, p.y); v1[j] = mk2(p.z, p.w);
    }
    dft8<1>(v0); dft8<1>(v1);
    twid_apply2(v0, v1, T[u<<6]);
    #pragma unroll
    for (int j = 0; j < 8; ++j)
        buf[s8 ^ ((j<<3)|(j>>1))] = make_float4(v0[j].x, v0[j].y, v1[j].x, v1[j].y);
    __syncthreads();

    // ---- DIF h=1 (stays in regs) ----
    #pragma unroll
    for (int j = 0; j < 8; ++j) {
        float4 p = buf[s1 ^ j];
        v0[j] = mk2(p.x, p.y); v1[j] = mk2(p.z, p.w);
    }
    dft8<1>(v0); dft8<1>(v1);

    // ---- instance norm + GELU (order-agnostic) ----
    v2f a0 = mk2(0.f,0.f), q0 = mk2(0.f,0.f), a1 = mk2(0.f,0.f), q1 = mk2(0.f,0.f);
    #pragma unroll
    for (int j = 0; j < 8; ++j) {
        a0 += v0[j]; q0 += v0[j]*v0[j];
        a1 += v1[j]; q1 += v1[j]*v1[j];
    }
    float ps0 = a0.x + a0.y, pq0 = q0.x + q0.y;
    float ps1 = a1.x + a1.y, pq1 = q1.x + q1.y;
    #pragma unroll
    for (int off = 32; off >= 1; off >>= 1) {
        ps0 += __shfl_down(ps0, off);  pq0 += __shfl_down(pq0, off);
        ps1 += __shfl_down(ps1, off);  pq1 += __shfl_down(pq1, off);
    }
    // leader writes its OWN h1 slot (s1(64w)^0 = 512w): no pre-barrier needed
    if ((t & 63) == 0) buf[(t>>6)<<9] = make_float4(ps0, pq0, ps1, pq1);
    __syncthreads();
    float sum0=0.f, sq0=0.f, sum1=0.f, sq1=0.f;
    #pragma unroll
    for (int w = 0; w < 8; ++w) {
        float4 p = buf[w<<9];
        sum0 += p.x; sq0 += p.y; sum1 += p.z; sq1 += p.w;
    }
    __syncthreads();   // partial reads done before DIT h=1 stores
    {
        float mean = sum0 * (1.0f/8192.0f);
        float var  = sq0  * (1.0f/8192.0f) - mean*mean;
        float gg = gamma[row0 & (kC-1)] * rsqrtf(var + 1e-5f);
        float bb = beta[row0 & (kC-1)] - mean * gg;
        #pragma unroll
        for (int j = 0; j < 8; ++j) v0[j] = gelu2(v0[j] * gg + bb);
    }
    {
        float mean = sum1 * (1.0f/8192.0f);
        float var  = sq1  * (1.0f/8192.0f) - mean*mean;
        float gg = gamma[(row0+1) & (kC-1)] * rsqrtf(var + 1e-5f);
        float bb = beta[(row0+1) & (kC-1)] - mean * gg;
        #pragma unroll
        for (int j = 0; j < 8; ++j) v1[j] = gelu2(v1[j] * gg + bb);
    }

    // ---- forward: DIT h=1 ----
    dft8<-1>(v0); dft8<-1>(v1);
    #pragma unroll
    for (int j = 0; j < 8; ++j)
        buf[s1 ^ j] = make_float4(v0[j].x, v0[j].y, v1[j].x, v1[j].y);
    __syncthreads();

    // ---- DIT h=8 ----
    #pragma unroll
    for (int j = 0; j < 8; ++j) {
        float4 p = buf[s8 ^ ((j<<3)|(j>>1))];
        v0[j] = mk2(p.x, p.y); v1[j] = mk2(p.z, p.w);
    }
    twid_apply2(v0, v1, cconj(T[u<<6]));
    dft8<-1>(v0); dft8<-1>(v1);
    #pragma unroll
    for (int j = 0; j < 8; ++j)
        buf[s8 ^ ((j<<3)|(j>>1))] = make_float4(v0[j].x, v0[j].y, v1[j].x, v1[j].y);
    __syncthreads();

    // ---- DIT h=64 ----
    #pragma unroll
    for (int j = 0; j < 8; ++j) {
        float4 p = buf[s64 ^ ((j<<6)|(j<<3)|((j&1)<<2))];
        v0[j] = mk2(p.x, p.y); v1[j] = mk2(p.z, p.w);
    }
    twid_apply2(v0, v1, cconj(T[l<<3]));
    dft8<-1>(v0); dft8<-1>(v1);
    #pragma unroll
    for (int j = 0; j < 8; ++j)
        buf[s64 ^ ((j<<6)|(j<<3)|((j&1)<<2))] = make_float4(v0[j].x, v0[j].y, v1[j].x, v1[j].y);
    __syncthreads();

    // ---- DIT h=512 (natural order out; stored for mirror access) ----
    #pragma unroll
    for (int j = 0; j < 8; ++j) {
        float4 p = buf[s0 + (j<<9)];
        v0[j] = mk2(p.x, p.y); v1[j] = mk2(p.z, p.w);
    }
    twid_apply2(v0, v1, cconj(T[t]));
    dft8<-1>(v0); dft8<-1>(v1);
    #pragma unroll
    for (int j = 0; j < 8; ++j)
        buf[s0 + (j<<9)] = make_float4(v0[j].x, v0[j].y, v1[j].x, v1[j].y);
    __syncthreads();

    // ---- post-combine (2*Y; 0.5s folded into k2 scale); both rows per j ----
    float* o0R = outR + (size_t)row0 * kN;
    float* o0I = outI + (size_t)row0 * kN;
    float* o1R = o0R + kN;
    float* o1I = o0I + kN;
    #pragma unroll
    for (int j = 0; j < 8; ++j) {
        int k = t + (j<<9);
        float4 pm = buf[swz((4096 - k) & 4095)];
        v2f w = W2048(T, k>>1);
        if (t & 1) w = cmul(w, E);
        w = cconj(w);
        {
            v2f Z = v0[j], Zm = mk2(pm.x, pm.y);
            v2f S = mk2(Z.x+Zm.x, Z.y-Zm.y);
            v2f D = mk2(Z.x-Zm.x, Z.y+Zm.y);
            v2f Y = S + mimul(cmul(D, w));
            o0R[k] = Y.x;  o0I[k] = Y.y;
        }
        {
            v2f Z = v1[j], Zm = mk2(pm.z, pm.w);
            v2f S = mk2(Z.x+Zm.x, Z.y-Zm.y);
            v2f D = mk2(Z.x-Zm.x, Z.y+Zm.y);
            v2f Y = S + mimul(cmul(D, w));
            o1R[k] = Y.x;  o1I[k] = Y.y;
        }
    }
    if (t == 0) {
        o0R[4096] = 2.0f*(v0[0].x - v0[0].y);  // 2*(Re Z'[0] - Im Z'[0])
        o0I[4096] = 0.f;
        o1R[4096] = 2.0f*(v1[0].x - v1[0].y);
        o1I[4096] = 0.f;
    }
}

// Kernel 2 (r5 version, ~HBM roofline): per (b, 32-wide k tile), kk in [0,4096]:
// 128-pt FFT along c, scale (incl. folded 0.5), bin rules, conj-mirror writes.
__global__ __launch_bounds__(256,4) void k2_col(float* __restrict__ outR,
                                                float* __restrict__ outI)
{
    __shared__ v2f tile[kC][32];  // 32 KiB
    __shared__ v2f tw[64];

    const int tid = threadIdx.x;
    const int k   = tid & 31;
    const int g   = tid >> 5;        // 0..7
    const int b   = blockIdx.y;
    const int kk  = (blockIdx.x << 5) + k;
    const bool valid = (kk <= 4096);

    if (tid < 64) {
        float s, c;
        sincosf((float)(kTwoPi/128.0 * (double)tid), &s, &c);
        tw[tid] = mk2(c, -s);
    }
    float* baseR = outR + (size_t)b * kC * kN;
    float* baseI = outI + (size_t)b * kC * kN;
    for (int c = g; c < kC; c += 8) {
        size_t off = (size_t)c * kN + kk;
        tile[c][k] = valid ? mk2(baseR[off], baseI[off]) : mk2(0.f, 0.f);
    }
    __syncthreads();

    for (int st = 7; st >= 1; --st) {
        const int h = 1 << (st-1);
        #pragma unroll
        for (int s = 0; s < 8; ++s) {
            int q   = g + (s<<3);
            int pos = q & (h-1);
            int i0  = ((q >> (st-1)) << st) + pos;
            int i1  = i0 + h;
            v2f a = tile[i0][k], bb = tile[i1][k];
            v2f w = tw[pos << (7-st)];
            tile[i0][k] = a + bb;
            tile[i1][k] = cmul(a - bb, w);
        }
        __syncthreads();
    }

    if (valid) {
        for (int p = g; p < kC; p += 8) {
            int f = (int)(__brev((unsigned)p) >> 25);
            v2f v = tile[p][k] * kScale;
            size_t off = (size_t)f * kN + kk;
            if (kk == 0 || kk == 4096) {
                baseR[off] = v.x; baseI[off] = 0.f;
            } else {
                baseR[off] = v.x; baseI[off] = v.y;
                size_t offm = (size_t)f * kN + (kN - kk);
                baseR[offm] = v.x; baseI[offm] = -v.y;
            }
        }
    }
}

extern "C" void kernel_launch(void* const* d_in, const int* in_sizes, int n_in,
                              void* d_out, int out_size, void* d_ws, size_t ws_size,
                              hipStream_t stream)
{
    const float* xr    = (const float*)d_in[0];
    const float* xi    = (const float*)d_in[1];
    const float* gamma = (const float*)d_in[2];
    const float* beta  = (const float*)d_in[3];

    float* outR = (float*)d_out;
    float* outI = outR + (size_t)kB * kC * kN;

    k1_row<<<kB * kC / 2, 512, 0, stream>>>(xr, xi, gamma, beta, outR, outI);
    k2_col<<<dim3(129, kB), 256, 0, stream>>>(outR, outI);
}